// Round 22
// baseline (785.057 us; speedup 1.0000x reference)
//
#include <hip/hip_runtime.h>
#include <math.h>

#define TWO_PI 6.283185307179586f

// HARNESS MODEL (verified R8-R21): d_out = 33,362,176 f32 = Re(out), [bc][l][m].
// Math: xr[c][k][m] = (2pi/720) * sum_n x[c][k][n] * cos(2pi n m/720)
//       out[c][l][m] = sum_k xr[c][k][m] * W[m][l][k]
// R22: s1 k-loop has ZERO barriers. B (cosine table) preloaded once into LDS
// for the full K (48 KB, swizzled); A per-lane in registers (R21-proven
// fragment layout). Only 8 global gathers/iter -> compiler can pipeline
// multiple iterations deep (R19's failure was 20 loads/iter at 44 VGPR).
// Rationale: cost-per-work-unit was invariant (~2800 cy) across R14-R21
// schedules; MFMA 11% + VALU 18% measured; remaining 70% = per-iteration
// vmcnt(0) drain at lockstep barriers. s2/transpose unchanged.

typedef __attribute__((ext_vector_type(8))) short bf16x8;
typedef __attribute__((ext_vector_type(4))) float f32x4;
typedef __attribute__((ext_vector_type(16))) float f32x16;

union BFU { uint4 u; bf16x8 v; };

__device__ inline unsigned short f2bf(float f) {
    union { float f; unsigned int u; } v; v.f = f;
    unsigned int u = v.u;
    return (unsigned short)((u + 0x7fffu + ((u >> 16) & 1u)) >> 16);  // RNE
}
__device__ inline float bf2f(unsigned short h) {
    union { unsigned int u; float f; } v; v.u = ((unsigned int)h) << 16;
    return v.f;
}
__device__ inline unsigned int packhl(float v) {
    unsigned short h = f2bf(v);
    unsigned short l = f2bf(v - bf2f(h));
    return (unsigned int)h | ((unsigned int)l << 16);
}
__device__ inline void split2(float a, float b, unsigned int& hh, unsigned int& ll) {
    unsigned short ha = f2bf(a), hb = f2bf(b);
    unsigned short la = f2bf(a - bf2f(ha)), lb = f2bf(b - bf2f(hb));
    hh = (unsigned int)ha | ((unsigned int)hb << 16);
    ll = (unsigned int)la | ((unsigned int)lb << 16);
}
// async global->LDS, 16B per lane; dest = wave-uniform base + lane*16
__device__ inline void gload_lds16(const void* g, void* l) {
    __builtin_amdgcn_global_load_lds(
        (const __attribute__((address_space(1))) unsigned int*)g,
        (__attribute__((address_space(3))) unsigned int*)l, 16, 0, 0);
}
// bijective chunked XCD swizzle (m204)
__device__ inline int xcd_work(int bid, int nwg) {
    int q = nwg >> 3, r = nwg & 7;
    int xcd = bid & 7, ord = bid >> 3;
    return (xcd < r ? xcd * (q + 1) : r * (q + 1) + (xcd - r) * q) + ord;
}

// ---------------- tables: EcT_hi/lo [384][384] bf16, EcT[m][n] = sigma*cos, n<=360 ----------------
__global__ void build_ect(unsigned short* __restrict__ Eh,
                          unsigned short* __restrict__ El) {
    const float sigma = TWO_PI / 720.0f;
    const int total = 384 * 384;
    for (int i = blockIdx.x * blockDim.x + threadIdx.x; i < total;
         i += gridDim.x * blockDim.x) {
        int m = i / 384, n = i % 384;
        float v = 0.f;
        if (m < 361 && n <= 360) {
            int r = (n * m) % 720;  // exact phase reduction
            v = sigma * cosf((float)r * (TWO_PI / 720.0f));
        }
        unsigned short h = f2bf(v);
        Eh[i] = h;
        El[i] = f2bf(v - bf2f(h));
    }
}

// ---------------- stage 1: xr[m][q] = sum_{n<=360} y[q][n]*EcT[m][n] ----------------
// y[n] = x[n]+x[720-n] (n=1..359), y0=x0, y360=x360.  Tile 128q x 32m,
// 4 waves (one 32-row q slice each). B: full-K LDS, preloaded once
// (chunk-swizzled c^=(row&7), both sides). A: per-lane reg fold+split.
// 12 k-iterations, NO barriers in the loop.
__global__ __launch_bounds__(256, 3) void s1_mfma(
    const float* __restrict__ x, const unsigned short* __restrict__ Eh,
    const unsigned short* __restrict__ El, unsigned int* __restrict__ xrp,
    const int Q) {
    __shared__ short Bt[2 * 32 * 48 * 8];   // 48 KB: chunk idx = (tab*32+row)*48+c

    const int work = xcd_work(blockIdx.x, gridDim.x);
    const int q0 = (work / 12) * 128;
    const int m0g = (work % 12) * 32;
    const int t = threadIdx.x;
    const int lane = t & 63, wv = t >> 6;
    const int lrow = lane & 31, lhk = lane >> 5;   // fragment row / k-half

    const int aq = q0 + wv * 32 + lrow;            // this lane's A (q) row
    const float* arow = x + (size_t)aq * 720;
    const bool qv = (aq < Q);

    // ---- B preload: 3072 chunks of 16B, thread id -> linear dest chunk id,
    // source chunk pre-swizzled c ^ (row&7) (rule #21: both sides) ----
#pragma unroll
    for (int i = 0; i < 12; ++i) {
        int id = t + i * 256;              // 0..3071 = (tab*32+row)*48 + c
        int tab = id / 1536, rem = id % 1536;
        int row = rem / 48, c = rem % 48;
        const unsigned short* src =
            (tab ? El : Eh) + (size_t)(m0g + row) * 384 + (c ^ (row & 7)) * 8;
        gload_lds16(src, (char*)Bt + id * 16);
    }
    __syncthreads();   // single barrier: B resident for the whole kernel

    // per-lane swizzled B chunk index helper
    const int rsw = lrow & 7;
    const int rbase = lrow * 48;           // tab=0 half; +1536 chunks for lo

    f32x16 acc;
#pragma unroll
    for (int r = 0; r < 16; ++r) acc[r] = 0.f;

    // ---- main loop: 12 iterations, no barriers; compiler pipelines loads ----
#pragma unroll
    for (int it = 0; it < 12; ++it) {
        float4 fw0, fw1, rv0, rv1;
        bf16x8 ah[2], al[2];
#pragma unroll
        for (int half = 0; half < 2; ++half) {
            const int kg = it * 32 + half * 16 + lhk * 8;
            fw0 = make_float4(0.f, 0.f, 0.f, 0.f);
            fw1 = fw0; rv0 = fw0; rv1 = fw0;
            if (qv) {
                if (kg <= 352) {
                    fw0 = *(const float4*)(arow + kg);
                    fw1 = *(const float4*)(arow + kg + 4);
                } else if (kg == 360) {
                    fw0.x = arow[360];
                }
                if (kg >= 8 && kg <= 352) {
                    rv0 = *(const float4*)(arow + 713 - kg);
                    rv1 = *(const float4*)(arow + 717 - kg);
                } else if (kg == 0) {
                    float tm[8];
#pragma unroll
                    for (int i = 0; i < 8; ++i)
                        tm[i] = (7 - i >= 1) ? arow[713 + i] : 0.f;
                    rv0 = make_float4(tm[0], tm[1], tm[2], tm[3]);
                    rv1 = make_float4(tm[4], tm[5], tm[6], tm[7]);
                }
            }
            float y0 = fw0.x + rv1.w, y1 = fw0.y + rv1.z;
            float y2 = fw0.z + rv1.y, y3 = fw0.w + rv1.x;
            float y4 = fw1.x + rv0.w, y5 = fw1.y + rv0.z;
            float y6 = fw1.z + rv0.y, y7 = fw1.w + rv0.x;
            BFU hu, lu;
            split2(y0, y1, hu.u.x, lu.u.x);
            split2(y2, y3, hu.u.y, lu.u.y);
            split2(y4, y5, hu.u.z, lu.u.z);
            split2(y6, y7, hu.u.w, lu.u.w);
            ah[half] = hu.v; al[half] = lu.v;
        }
        // B fragments from LDS (swizzled chunk index)
        const int l0c = (it * 4 + 0 * 2 + lhk) ^ rsw;
        const int l1c = (it * 4 + 1 * 2 + lhk) ^ rsw;
        bf16x8 bh0 = *(const bf16x8*)((const char*)Bt + (rbase + l0c) * 16);
        bf16x8 bl0 = *(const bf16x8*)((const char*)Bt + (1536 + rbase + l0c) * 16);
        bf16x8 bh1 = *(const bf16x8*)((const char*)Bt + (rbase + l1c) * 16);
        bf16x8 bl1 = *(const bf16x8*)((const char*)Bt + (1536 + rbase + l1c) * 16);
        acc = __builtin_amdgcn_mfma_f32_32x32x16_bf16(ah[0], bh0, acc, 0, 0, 0);
        acc = __builtin_amdgcn_mfma_f32_32x32x16_bf16(ah[0], bl0, acc, 0, 0, 0);
        acc = __builtin_amdgcn_mfma_f32_32x32x16_bf16(al[0], bh0, acc, 0, 0, 0);
        acc = __builtin_amdgcn_mfma_f32_32x32x16_bf16(ah[1], bh1, acc, 0, 0, 0);
        acc = __builtin_amdgcn_mfma_f32_32x32x16_bf16(ah[1], bl1, acc, 0, 0, 0);
        acc = __builtin_amdgcn_mfma_f32_32x32x16_bf16(al[1], bh1, acc, 0, 0, 0);
    }

    // epilogue: 32x32 D map: col(m)=lane&31, row(q)=(r&3)+8*(r>>2)+4*(lane>>5)
    const int m = m0g + lrow;
    if (m < 361) {
        size_t base = (size_t)m * Q;
#pragma unroll
        for (int r = 0; r < 16; ++r) {
            int q = q0 + wv * 32 + (r & 3) + 8 * (r >> 2) + 4 * lhk;
            if (q < Q) xrp[base + q] = packhl(acc[r]);
        }
    }
}

// ---------------- stage 2: per-m GEMM, tile 128bc x 64l (R14 proven form) ----------------
__global__ __launch_bounds__(256, 4) void s2_mfma(
    const unsigned int* __restrict__ xrp, const float* __restrict__ W,
    float* __restrict__ stg, const int CH) {
    __shared__ short Ah[128][40], Al[128][40];   // 10 KB each
    __shared__ short Bh[64][40], Bl[64][40];     // 5 KB each -> 30 KB

    const int work = xcd_work(blockIdx.x, gridDim.x);
    const int m = work / 12;
    const int rem = work % 12;
    const int half = rem / 6, lt = rem % 6;
    const int l0 = lt * 64;
    if (l0 + 63 < m) return;          // dead tile: zero-filled by transpose
    const int bcbase = half * 128;
    if (bcbase >= CH) return;
    const int Q = CH * 361;
    const int t = threadIdx.x;
    const int lane = t & 63, wv = t >> 6;
    const int lr = lane & 15, lk = lane >> 4;
    const int wbc = wv >> 1, wl = wv & 1;

    const unsigned int* Am = xrp + (size_t)m * Q;
    const float* Wm = W + (size_t)m * 130321;

    f32x4 acc[4][2];
#pragma unroll
    for (int fi = 0; fi < 4; ++fi)
#pragma unroll
        for (int ni = 0; ni < 2; ++ni)
#pragma unroll
            for (int r = 0; r < 4; ++r) acc[fi][ni][r] = 0.f;

    unsigned int pa0[8], pa1[8];
    float wva[4], wvb[4];

#define S2_LOADR(K0)                                                          \
    {                                                                         \
        _Pragma("unroll") for (int i = 0; i < 8; ++i) {                       \
            int id = t + i * 256;                                             \
            int r = id >> 4, kp = id & 15;                                    \
            int bc = bcbase + r, kg = (K0) + kp * 2;                          \
            unsigned int p0 = 0, p1 = 0;                                      \
            if (bc < CH) {                                                    \
                size_t base = (size_t)bc * 361;                               \
                if (kg < 361) p0 = Am[base + kg];                             \
                if (kg + 1 < 361) p1 = Am[base + kg + 1];                     \
            }                                                                 \
            pa0[i] = p0; pa1[i] = p1;                                         \
        }                                                                     \
        _Pragma("unroll") for (int i = 0; i < 4; ++i) {                       \
            int id = t + i * 256;                                             \
            int r = id >> 4, kp = id & 15;                                    \
            int l = l0 + r, kg = (K0) + kp * 2;                               \
            float va = 0.f, vb = 0.f;                                         \
            if (l < 361) {                                                    \
                size_t base = (size_t)l * 361;                                \
                if (kg < 361) va = Wm[base + kg];                             \
                if (kg + 1 < 361) vb = Wm[base + kg + 1];                     \
            }                                                                 \
            wva[i] = va; wvb[i] = vb;                                         \
        }                                                                     \
    }
#define S2_WRITES()                                                           \
    {                                                                         \
        _Pragma("unroll") for (int i = 0; i < 8; ++i) {                       \
            int id = t + i * 256;                                             \
            int r = id >> 4, kp = id & 15;                                    \
            *(unsigned int*)&Ah[r][kp * 2] =                                  \
                (pa0[i] & 0xffffu) | (pa1[i] << 16);                          \
            *(unsigned int*)&Al[r][kp * 2] =                                  \
                (pa0[i] >> 16) | (pa1[i] & 0xffff0000u);                      \
        }                                                                     \
        _Pragma("unroll") for (int i = 0; i < 4; ++i) {                       \
            int id = t + i * 256;                                             \
            int r = id >> 4, kp = id & 15;                                    \
            unsigned int hh, ll;                                              \
            split2(wva[i], wvb[i], hh, ll);                                   \
            *(unsigned int*)&Bh[r][kp * 2] = hh;                              \
            *(unsigned int*)&Bl[r][kp * 2] = ll;                              \
        }                                                                     \
    }

    S2_LOADR(0);
    S2_WRITES();
    __syncthreads();
    for (int it = 0; it < 12; ++it) {
        if (it + 1 < 12) S2_LOADR((it + 1) * 32);
#pragma unroll
        for (int fi = 0; fi < 4; ++fi) {
            bf16x8 ah = *(const bf16x8*)&Ah[wbc * 64 + fi * 16 + lr][lk * 8];
            bf16x8 al = *(const bf16x8*)&Al[wbc * 64 + fi * 16 + lr][lk * 8];
#pragma unroll
            for (int ni = 0; ni < 2; ++ni) {
                bf16x8 bh = *(const bf16x8*)&Bh[wl * 32 + ni * 16 + lr][lk * 8];
                bf16x8 bl = *(const bf16x8*)&Bl[wl * 32 + ni * 16 + lr][lk * 8];
                acc[fi][ni] = __builtin_amdgcn_mfma_f32_16x16x32_bf16(ah, bh, acc[fi][ni], 0, 0, 0);
                acc[fi][ni] = __builtin_amdgcn_mfma_f32_16x16x32_bf16(ah, bl, acc[fi][ni], 0, 0, 0);
                acc[fi][ni] = __builtin_amdgcn_mfma_f32_16x16x32_bf16(al, bh, acc[fi][ni], 0, 0, 0);
            }
        }
        __syncthreads();
        if (it + 1 < 12) {
            S2_WRITES();
            __syncthreads();
        }
    }

    // epilogue: stg[(m*CH+bc)*361+l]
#pragma unroll
    for (int fi = 0; fi < 4; ++fi) {
#pragma unroll
        for (int ni = 0; ni < 2; ++ni) {
            int l = l0 + wl * 32 + ni * 16 + lr;
#pragma unroll
            for (int reg = 0; reg < 4; ++reg) {
                int bc = bcbase + wbc * 64 + fi * 16 + lk * 4 + reg;
                if (bc < CH && l < 361)
                    stg[((size_t)m * CH + bc) * 361 + l] = acc[fi][ni][reg];
            }
        }
    }
}

// ---------------- transpose stg [m][q'] -> out, zero-filling dead tiles ----------------
__global__ __launch_bounds__(256) void transpose_out(const float* __restrict__ stg,
                                                     float* __restrict__ out,
                                                     const int c0, const int CH) {
    __shared__ float tile[32][33];
    const int Q = CH * 361;
    const int m0 = blockIdx.y * 32, q0 = blockIdx.x * 32;
    const int tx = threadIdx.x & 31, ty = threadIdx.x >> 5;
    for (int i = ty; i < 32; i += 8) {
        int mm = m0 + i, q = q0 + tx;
        float v = 0.f;
        if (mm < 361 && q < Q) {
            int l = q % 361;
            if ((l | 63) >= mm) v = stg[(size_t)mm * Q + q];  // live 64-tile
        }
        tile[i][tx] = v;
    }
    __syncthreads();
    for (int i = ty; i < 32; i += 8) {
        int q = q0 + i, mm = m0 + tx;
        if (mm < 361 && q < Q)
            out[((size_t)c0 * 361 + q) * 361 + mm] = tile[tx][i];
    }
}

extern "C" void kernel_launch(void* const* d_in, const int* in_sizes, int n_in,
                              void* d_out, int out_size, void* d_ws, size_t ws_size,
                              hipStream_t stream) {
    (void)out_size;
    // select inputs by element count: x = 66,539,520; W = 47,045,881
    const float* x = (const float*)d_in[0];
    const float* W = (const float*)d_in[1];
    if (n_in >= 2 && (in_sizes[0] == 47045881 || in_sizes[1] == 66539520)) {
        x = (const float*)d_in[1];
        W = (const float*)d_in[0];
    }
    float* out = (float*)d_out;

    // ws layout (bytes): EcT_hi [384][384] | EcT_lo | xrp (uint) | stg (f32)
    const size_t offEh = 0;
    const size_t offEl = 294912;                 // 384*384*2
    const size_t offData = 589824;

    const int cands[6] = {256, 128, 64, 32, 16, 8};
    int CH = 0;
    for (int i = 0; i < 6; ++i) {
        size_t need = offData + 2ull * cands[i] * 130321ull * 4ull;
        if (need <= ws_size) { CH = cands[i]; break; }
    }
    if (!CH) return;  // workspace too small: fail visibly, don't fault

    unsigned short* Eh = (unsigned short*)((char*)d_ws + offEh);
    unsigned short* El = (unsigned short*)((char*)d_ws + offEl);
    unsigned int* xrp = (unsigned int*)((char*)d_ws + offData);
    float* stg = (float*)((char*)d_ws + offData + (size_t)CH * 130321ull * 4ull);

    build_ect<<<256, 256, 0, stream>>>(Eh, El);

    const int Q = CH * 361;
    const int qt = (Q + 127) / 128;
    for (int c0 = 0; c0 < 256; c0 += CH) {
        s1_mfma<<<qt * 12, 256, 0, stream>>>(
            x + (size_t)c0 * 361 * 720, Eh, El, xrp, Q);
        s2_mfma<<<361 * 12, 256, 0, stream>>>(xrp, W, stg, CH);
        transpose_out<<<dim3((Q + 31) / 32, 12), 256, 0, stream>>>(stg, out, c0, CH);
    }
}

// Round 23
// 674.751 us; speedup vs baseline: 1.1635x; 1.1635x over previous
//
#include <hip/hip_runtime.h>
#include <math.h>

#define TWO_PI 6.283185307179586f

// HARNESS MODEL (verified R8-R22): d_out = 33,362,176 f32 = Re(out), [bc][l][m].
// Math: xr[c][k][m] = (2pi/720) * sum_n x[c][k][n] * cos(2pi n m/720)
//       out[c][l][m] = sum_k xr[c][k][m] * W[m][l][k]
// R23: s1 = R20's proven pipeline, but its epilogue writes SEPARATE hi/lo
// bf16 planes xh/xl laid out [m][bc][368] (16B-aligned k-runs). s2's
// A-fragments are then direct bf16x8 global loads (L2-resident panel):
// no A-unpack, no A-LDS, no A-staging. s2 LDS 30->10 KB (W dbuf only).

typedef __attribute__((ext_vector_type(8))) short bf16x8;
typedef __attribute__((ext_vector_type(4))) float f32x4;

__device__ inline unsigned short f2bf(float f) {
    union { float f; unsigned int u; } v; v.f = f;
    unsigned int u = v.u;
    return (unsigned short)((u + 0x7fffu + ((u >> 16) & 1u)) >> 16);  // RNE
}
__device__ inline float bf2f(unsigned short h) {
    union { unsigned int u; float f; } v; v.u = ((unsigned int)h) << 16;
    return v.f;
}
__device__ inline void split2(float a, float b, unsigned int& hh, unsigned int& ll) {
    unsigned short ha = f2bf(a), hb = f2bf(b);
    unsigned short la = f2bf(a - bf2f(ha)), lb = f2bf(b - bf2f(hb));
    hh = (unsigned int)ha | ((unsigned int)hb << 16);
    ll = (unsigned int)la | ((unsigned int)lb << 16);
}
// truncation split (R17-proven for s1 A-path)
__device__ inline void split2t(float a, float b, unsigned int& hh, unsigned int& ll) {
    union { float f; unsigned int u; } ua, ub, fa, fb, la, lb;
    ua.f = a; ub.f = b;
    hh = (ua.u >> 16) | (ub.u & 0xffff0000u);
    fa.u = ua.u & 0xffff0000u;
    fb.u = ub.u & 0xffff0000u;
    la.f = a - fa.f;
    lb.f = b - fb.f;
    ll = (la.u >> 16) | (lb.u & 0xffff0000u);
}
// async global->LDS, 16B per lane; dest = wave-uniform base + lane*16
__device__ inline void gload_lds16(const void* g, void* l) {
    __builtin_amdgcn_global_load_lds(
        (const __attribute__((address_space(1))) unsigned int*)g,
        (__attribute__((address_space(3))) unsigned int*)l, 16, 0, 0);
}
// bijective chunked XCD swizzle (m204)
__device__ inline int xcd_work(int bid, int nwg) {
    int q = nwg >> 3, r = nwg & 7;
    int xcd = bid & 7, ord = bid >> 3;
    return (xcd < r ? xcd * (q + 1) : r * (q + 1) + (xcd - r) * q) + ord;
}

// ---------------- tables: EcT_hi/lo [384][384] bf16, EcT[m][n] = sigma*cos, n<=360 ----------------
__global__ void build_ect(unsigned short* __restrict__ Eh,
                          unsigned short* __restrict__ El) {
    const float sigma = TWO_PI / 720.0f;
    const int total = 384 * 384;
    for (int i = blockIdx.x * blockDim.x + threadIdx.x; i < total;
         i += gridDim.x * blockDim.x) {
        int m = i / 384, n = i % 384;
        float v = 0.f;
        if (m < 361 && n <= 360) {
            int r = (n * m) % 720;  // exact phase reduction
            v = sigma * cosf((float)r * (TWO_PI / 720.0f));
        }
        unsigned short h = f2bf(v);
        Eh[i] = h;
        El[i] = f2bf(v - bf2f(h));
    }
}

// ---------------- stage 1 (R20 proven): xh/xl[m][bc][368] = split(xr) ----------------
// y[n] = x[n]+x[720-n] (n=1..359), y0=x0, y360=x360.  12 iters, dbuf,
// 1 barrier/iter; B staged via global_load_lds; A scalar reg-prefetch.
__global__ __launch_bounds__(256, 4) void s1_mfma(
    const float* __restrict__ x, const unsigned short* __restrict__ Eh,
    const unsigned short* __restrict__ El, unsigned short* __restrict__ xh,
    unsigned short* __restrict__ xl, const int Q, const int CH) {
    __shared__ short Ah[2][4][64][8], Al[2][4][64][8];   // 16 KB
    __shared__ short Bt[2][2][4][96][8];                 // 24.5 KB -> 40 KB total

    const int work = xcd_work(blockIdx.x, gridDim.x);
    const int q0 = (work >> 2) * 64;
    const int m0g = (work & 3) * 96;
    const int t = threadIdx.x;
    const int lane = t & 63, wv = t >> 6;
    const int lr = lane & 15, lk = lane >> 4;
    const int wq = wv;

    const int ar = t >> 2, akc = t & 3;
    const int aq = q0 + ar;
    const float* arow = x + (size_t)aq * 720;
    const bool aqv = (aq < Q);

    const unsigned short* bsrc[3];
#pragma unroll
    for (int i = 0; i < 3; ++i) {
        int id = t + i * 256;
        int tab = id / 384, rem = id % 384;
        int kc = rem / 96, r = rem % 96;
        bsrc[i] = (tab ? El : Eh) + (size_t)(m0g + r) * 384 + kc * 8;
    }

    f32x4 acc[6];
#pragma unroll
    for (int nj = 0; nj < 6; ++nj)
#pragma unroll
        for (int r = 0; r < 4; ++r) acc[nj][r] = 0.f;

    float4 f0a, f0b, pra, prb;

#define S1_LOADA(K0)                                                       \
    {                                                                      \
        int kg = (K0) + akc * 8;                                           \
        f0a = make_float4(0.f, 0.f, 0.f, 0.f);                             \
        f0b = f0a; pra = f0a; prb = f0a;                                   \
        if (aqv) {                                                         \
            if (kg <= 352) {                                               \
                f0a = *(const float4*)(arow + kg);                         \
                f0b = *(const float4*)(arow + kg + 4);                     \
            } else if (kg == 360) {                                        \
                f0a.x = arow[360];                                         \
            }                                                              \
            if (kg >= 8 && kg <= 352) {                                    \
                pra = *(const float4*)(arow + 713 - kg);                   \
                prb = *(const float4*)(arow + 717 - kg);                   \
            } else if (kg == 0) {                                          \
                float tm[8];                                               \
                _Pragma("unroll") for (int i = 0; i < 8; ++i) {            \
                    int n = 7 - i;                                         \
                    tm[i] = (n >= 1) ? arow[713 + i] : 0.f;                \
                }                                                          \
                pra = make_float4(tm[0], tm[1], tm[2], tm[3]);             \
                prb = make_float4(tm[4], tm[5], tm[6], tm[7]);             \
            }                                                              \
        }                                                                  \
    }
#define S1_WRITEA(NB)                                                     \
    {                                                                     \
        float y0 = f0a.x + prb.w, y1 = f0a.y + prb.z;                     \
        float y2 = f0a.z + prb.y, y3 = f0a.w + prb.x;                     \
        float y4 = f0b.x + pra.w, y5 = f0b.y + pra.z;                     \
        float y6 = f0b.z + pra.y, y7 = f0b.w + pra.x;                     \
        unsigned int h0, h1, h2, h3, l0, l1, l2, l3;                      \
        split2t(y0, y1, h0, l0);                                          \
        split2t(y2, y3, h1, l1);                                          \
        split2t(y4, y5, h2, l2);                                          \
        split2t(y6, y7, h3, l3);                                          \
        *(uint4*)&Ah[NB][akc][ar][0] = make_uint4(h0, h1, h2, h3);        \
        *(uint4*)&Al[NB][akc][ar][0] = make_uint4(l0, l1, l2, l3);        \
    }
#define S1_COPYB(NB, K0)                                                  \
    {                                                                     \
        char* bb = (char*)&Bt[NB][0][0][0][0];                            \
        _Pragma("unroll") for (int i = 0; i < 3; ++i) {                   \
            gload_lds16(bsrc[i] + (K0), bb + (t + i * 256) * 16);         \
        }                                                                 \
    }

    S1_COPYB(0, 0);
    S1_LOADA(0);
    S1_WRITEA(0);
    __syncthreads();
    int cur = 0;
    const int NIT = 12;
    for (int it = 0; it < NIT; ++it) {
        const int nb = cur ^ 1;
        if (it + 1 < NIT) {
            S1_COPYB(nb, (it + 1) * 32);
            S1_LOADA((it + 1) * 32);
        }
        bf16x8 ah = *(const bf16x8*)&Ah[cur][lk][wq * 16 + lr][0];
        bf16x8 al = *(const bf16x8*)&Al[cur][lk][wq * 16 + lr][0];
#pragma unroll
        for (int nj = 0; nj < 6; ++nj) {
            bf16x8 bh = *(const bf16x8*)&Bt[cur][0][lk][nj * 16 + lr][0];
            bf16x8 bl = *(const bf16x8*)&Bt[cur][1][lk][nj * 16 + lr][0];
            acc[nj] = __builtin_amdgcn_mfma_f32_16x16x32_bf16(ah, bh, acc[nj], 0, 0, 0);
            acc[nj] = __builtin_amdgcn_mfma_f32_16x16x32_bf16(ah, bl, acc[nj], 0, 0, 0);
            acc[nj] = __builtin_amdgcn_mfma_f32_16x16x32_bf16(al, bh, acc[nj], 0, 0, 0);
        }
        if (it + 1 < NIT) {
            S1_WRITEA(nb);
            __syncthreads();
            cur = nb;
        }
    }

    // epilogue: write hi/lo planes [m][bc][368]; q -> (bc, lat)
#pragma unroll
    for (int nj = 0; nj < 6; ++nj) {
        int m = m0g + nj * 16 + lr;
        if (m >= 361) continue;
        size_t mbase = (size_t)m * CH;
#pragma unroll
        for (int reg = 0; reg < 4; ++reg) {
            int q = q0 + wq * 16 + lk * 4 + reg;
            if (q < Q) {
                int bc = q / 361;
                int lat = q - bc * 361;
                size_t o = (mbase + bc) * 368 + lat;
                float v = acc[nj][reg];
                unsigned short h = f2bf(v);
                xh[o] = h;
                xl[o] = f2bf(v - bf2f(h));
            }
        }
    }
}

// ---------------- stage 2: per-m GEMM, A direct from xh/xl, W-dbuf LDS ----------------
// 256 thr = 4 waves (2 bc-sub x 2 l-sub); grid 361*12 flattened+swizzled
__global__ __launch_bounds__(256, 4) void s2_mfma(
    const unsigned short* __restrict__ xh, const unsigned short* __restrict__ xl,
    const float* __restrict__ W, float* __restrict__ stg, const int CH) {
    __shared__ short Bh[64][40], Bl[64][40];     // 10 KB total

    const int work = xcd_work(blockIdx.x, gridDim.x);
    const int m = work / 12;
    const int rem = work % 12;
    const int half = rem / 6, lt = rem % 6;
    const int l0 = lt * 64;
    if (l0 + 63 < m) return;          // dead tile: zero-filled by transpose
    const int bcbase = half * 128;
    if (bcbase >= CH) return;
    const int t = threadIdx.x;
    const int lane = t & 63, wv = t >> 6;
    const int lr = lane & 15, lk = lane >> 4;
    const int wbc = wv >> 1, wl = wv & 1;

    const unsigned short* Axh = xh + (size_t)m * CH * 368;
    const unsigned short* Axl = xl + (size_t)m * CH * 368;
    const float* Wm = W + (size_t)m * 130321;

    // per-lane A row indices (clamped for small CH; results discarded then)
    int arow[4];
#pragma unroll
    for (int fi = 0; fi < 4; ++fi) {
        int bc = bcbase + wbc * 64 + fi * 16 + lr;
        arow[fi] = (bc < CH) ? bc : 0;
    }

    f32x4 acc[4][2];
#pragma unroll
    for (int fi = 0; fi < 4; ++fi)
#pragma unroll
        for (int ni = 0; ni < 2; ++ni)
#pragma unroll
            for (int r = 0; r < 4; ++r) acc[fi][ni][r] = 0.f;

    float wva[4], wvb[4];

#define S2_LOADW(K0)                                                          \
    {                                                                         \
        _Pragma("unroll") for (int i = 0; i < 4; ++i) {                       \
            int id = t + i * 256;                                             \
            int r = id >> 4, kp = id & 15;                                    \
            int l = l0 + r, kg = (K0) + kp * 2;                               \
            float va = 0.f, vb = 0.f;                                         \
            if (l < 361) {                                                    \
                size_t base = (size_t)l * 361;                                \
                if (kg < 361) va = Wm[base + kg];                             \
                if (kg + 1 < 361) vb = Wm[base + kg + 1];                     \
            }                                                                 \
            wva[i] = va; wvb[i] = vb;                                         \
        }                                                                     \
    }
#define S2_WRITEW()                                                           \
    {                                                                         \
        _Pragma("unroll") for (int i = 0; i < 4; ++i) {                       \
            int id = t + i * 256;                                             \
            int r = id >> 4, kp = id & 15;                                    \
            unsigned int hh, ll;                                              \
            split2(wva[i], wvb[i], hh, ll);                                   \
            *(unsigned int*)&Bh[r][kp * 2] = hh;                              \
            *(unsigned int*)&Bl[r][kp * 2] = ll;                              \
        }                                                                     \
    }

    S2_LOADW(0);
    S2_WRITEW();
    __syncthreads();
    for (int it = 0; it < 12; ++it) {
        if (it + 1 < 12) S2_LOADW((it + 1) * 32);
        const int koff = it * 32 + lk * 8;
#pragma unroll
        for (int fi = 0; fi < 4; ++fi) {
            size_t abase = (size_t)arow[fi] * 368 + koff;
            bf16x8 ah = *(const bf16x8*)(Axh + abase);   // 16B aligned (368%8==0)
            bf16x8 al = *(const bf16x8*)(Axl + abase);
#pragma unroll
            for (int ni = 0; ni < 2; ++ni) {
                bf16x8 bh = *(const bf16x8*)&Bh[wl * 32 + ni * 16 + lr][lk * 8];
                bf16x8 bl = *(const bf16x8*)&Bl[wl * 32 + ni * 16 + lr][lk * 8];
                acc[fi][ni] = __builtin_amdgcn_mfma_f32_16x16x32_bf16(ah, bh, acc[fi][ni], 0, 0, 0);
                acc[fi][ni] = __builtin_amdgcn_mfma_f32_16x16x32_bf16(ah, bl, acc[fi][ni], 0, 0, 0);
                acc[fi][ni] = __builtin_amdgcn_mfma_f32_16x16x32_bf16(al, bh, acc[fi][ni], 0, 0, 0);
            }
        }
        __syncthreads();
        if (it + 1 < 12) {
            S2_WRITEW();
            __syncthreads();
        }
    }

    // epilogue: stg[(m*CH+bc)*361+l]
#pragma unroll
    for (int fi = 0; fi < 4; ++fi) {
#pragma unroll
        for (int ni = 0; ni < 2; ++ni) {
            int l = l0 + wl * 32 + ni * 16 + lr;
#pragma unroll
            for (int reg = 0; reg < 4; ++reg) {
                int bc = bcbase + wbc * 64 + fi * 16 + lk * 4 + reg;
                if (bc < CH && l < 361)
                    stg[((size_t)m * CH + bc) * 361 + l] = acc[fi][ni][reg];
            }
        }
    }
}

// ---------------- transpose stg [m][q'] -> out, zero-filling dead tiles ----------------
__global__ __launch_bounds__(256) void transpose_out(const float* __restrict__ stg,
                                                     float* __restrict__ out,
                                                     const int c0, const int CH) {
    __shared__ float tile[32][33];
    const int Q = CH * 361;
    const int m0 = blockIdx.y * 32, q0 = blockIdx.x * 32;
    const int tx = threadIdx.x & 31, ty = threadIdx.x >> 5;
    for (int i = ty; i < 32; i += 8) {
        int mm = m0 + i, q = q0 + tx;
        float v = 0.f;
        if (mm < 361 && q < Q) {
            int l = q % 361;
            if ((l | 63) >= mm) v = stg[(size_t)mm * Q + q];  // live 64-tile
        }
        tile[i][tx] = v;
    }
    __syncthreads();
    for (int i = ty; i < 32; i += 8) {
        int q = q0 + i, mm = m0 + tx;
        if (mm < 361 && q < Q)
            out[((size_t)c0 * 361 + q) * 361 + mm] = tile[tx][i];
    }
}

extern "C" void kernel_launch(void* const* d_in, const int* in_sizes, int n_in,
                              void* d_out, int out_size, void* d_ws, size_t ws_size,
                              hipStream_t stream) {
    (void)out_size;
    // select inputs by element count: x = 66,539,520; W = 47,045,881
    const float* x = (const float*)d_in[0];
    const float* W = (const float*)d_in[1];
    if (n_in >= 2 && (in_sizes[0] == 47045881 || in_sizes[1] == 66539520)) {
        x = (const float*)d_in[1];
        W = (const float*)d_in[0];
    }
    float* out = (float*)d_out;

    // ws layout (bytes): EcT_hi | EcT_lo | xh | xl (ushort, 361*CH*368 each) | stg
    const size_t offEh = 0;
    const size_t offEl = 294912;                 // 384*384*2
    const size_t offData = 589824;

    const int cands[6] = {256, 128, 64, 32, 16, 8};
    int CH = 0;
    for (int i = 0; i < 6; ++i) {
        size_t planes = 2ull * 361 * cands[i] * 368 * 2;          // xh+xl bytes
        size_t need = offData + planes + (size_t)cands[i] * 130321ull * 4ull;
        if (need <= ws_size) { CH = cands[i]; break; }
    }
    if (!CH) return;  // workspace too small: fail visibly, don't fault

    unsigned short* Eh = (unsigned short*)((char*)d_ws + offEh);
    unsigned short* El = (unsigned short*)((char*)d_ws + offEl);
    unsigned short* xhp = (unsigned short*)((char*)d_ws + offData);
    const size_t planeElems = (size_t)361 * CH * 368;
    unsigned short* xlp = xhp + planeElems;
    float* stg = (float*)((char*)d_ws + offData + 2 * planeElems * 2);

    build_ect<<<256, 256, 0, stream>>>(Eh, El);

    const int Q = CH * 361;
    const int qt = (Q + 63) / 64;
    for (int c0 = 0; c0 < 256; c0 += CH) {
        s1_mfma<<<qt * 4, 256, 0, stream>>>(
            x + (size_t)c0 * 361 * 720, Eh, El, xhp, xlp, Q, CH);
        s2_mfma<<<361 * 12, 256, 0, stream>>>(xhp, xlp, W, stg, CH);
        transpose_out<<<dim3((Q + 31) / 32, 12), 256, 0, stream>>>(stg, out, c0, CH);
    }
}

// Round 24
// 599.319 us; speedup vs baseline: 1.3099x; 1.1259x over previous
//
#include <hip/hip_runtime.h>
#include <math.h>

#define TWO_PI 6.283185307179586f

// HARNESS MODEL (verified R8-R23): d_out = 33,362,176 f32 = Re(out), [bc][l][m].
// Math: xr[c][k][m] = (2pi/720) * sum_n x[c][k][n] * cos(2pi n m/720)
//       out[c][l][m] = sum_k xr[c][k][m] * W[m][l][k]
// R24 = R20 base + s1 counted-vmcnt barrier (T4): A-loads prefetched 2 deep
// and left IN FLIGHT across a raw s_barrier via "s_waitcnt vmcnt(4)" (drains
// only the 3 B-DMAs). A-loads are made UNIFORM (exactly 4/thread/iter,
// clamped+masked) so per-wave vmcnt counting is exact. Issue order pinned
// with sched_barrier(0). A-staging is wave-private (wave writes/reads only
// its own 16 rows), so only B requires the barrier. s2/transpose = R20.

typedef __attribute__((ext_vector_type(8))) short bf16x8;
typedef __attribute__((ext_vector_type(4))) float f32x4;

__device__ inline unsigned short f2bf(float f) {
    union { float f; unsigned int u; } v; v.f = f;
    unsigned int u = v.u;
    return (unsigned short)((u + 0x7fffu + ((u >> 16) & 1u)) >> 16);  // RNE
}
__device__ inline float bf2f(unsigned short h) {
    union { unsigned int u; float f; } v; v.u = ((unsigned int)h) << 16;
    return v.f;
}
__device__ inline unsigned int packhl(float v) {
    unsigned short h = f2bf(v);
    unsigned short l = f2bf(v - bf2f(h));
    return (unsigned int)h | ((unsigned int)l << 16);
}
__device__ inline void split2(float a, float b, unsigned int& hh, unsigned int& ll) {
    unsigned short ha = f2bf(a), hb = f2bf(b);
    unsigned short la = f2bf(a - bf2f(ha)), lb = f2bf(b - bf2f(hb));
    hh = (unsigned int)ha | ((unsigned int)hb << 16);
    ll = (unsigned int)la | ((unsigned int)lb << 16);
}
// truncation split (R17/R20-proven for s1 A-path)
__device__ inline void split2t(float a, float b, unsigned int& hh, unsigned int& ll) {
    union { float f; unsigned int u; } ua, ub, fa, fb, la, lb;
    ua.f = a; ub.f = b;
    hh = (ua.u >> 16) | (ub.u & 0xffff0000u);
    fa.u = ua.u & 0xffff0000u;
    fb.u = ub.u & 0xffff0000u;
    la.f = a - fa.f;
    lb.f = b - fb.f;
    ll = (la.u >> 16) | (lb.u & 0xffff0000u);
}
// async global->LDS, 16B per lane; dest = wave-uniform base + lane*16
__device__ inline void gload_lds16(const void* g, void* l) {
    __builtin_amdgcn_global_load_lds(
        (const __attribute__((address_space(1))) unsigned int*)g,
        (__attribute__((address_space(3))) unsigned int*)l, 16, 0, 0);
}
// bijective chunked XCD swizzle (m204)
__device__ inline int xcd_work(int bid, int nwg) {
    int q = nwg >> 3, r = nwg & 7;
    int xcd = bid & 7, ord = bid >> 3;
    return (xcd < r ? xcd * (q + 1) : r * (q + 1) + (xcd - r) * q) + ord;
}

// ---------------- tables: EcT_hi/lo [384][384] bf16, EcT[m][n] = sigma*cos, n<=360 ----------------
__global__ void build_ect(unsigned short* __restrict__ Eh,
                          unsigned short* __restrict__ El) {
    const float sigma = TWO_PI / 720.0f;
    const int total = 384 * 384;
    for (int i = blockIdx.x * blockDim.x + threadIdx.x; i < total;
         i += gridDim.x * blockDim.x) {
        int m = i / 384, n = i % 384;
        float v = 0.f;
        if (m < 361 && n <= 360) {
            int r = (n * m) % 720;  // exact phase reduction
            v = sigma * cosf((float)r * (TWO_PI / 720.0f));
        }
        unsigned short h = f2bf(v);
        Eh[i] = h;
        El[i] = f2bf(v - bf2f(h));
    }
}

// ---------------- stage 1: xr[m][q] = sum_{n<=360} y[q][n]*EcT[m][n] ----------------
// y[n] = x[n]+x[720-n] (n=1..359), y0=x0, y360=x360.  12 iters, A/B LDS dbuf,
// ONE raw barrier per iter with counted vmcnt(4): B-DMAs drained, 2-deep
// A-prefetch stays in flight across the barrier.
__global__ __launch_bounds__(256, 4) void s1_mfma(
    const float* __restrict__ x, const unsigned short* __restrict__ Eh,
    const unsigned short* __restrict__ El, unsigned int* __restrict__ xrp,
    const int Q) {
    __shared__ short Ah[2][4][64][8], Al[2][4][64][8];   // 16 KB
    __shared__ short Bt[2][2][4][96][8];                 // 24.5 KB -> 40 KB total

    const int work = xcd_work(blockIdx.x, gridDim.x);
    const int q0 = (work >> 2) * 64;
    const int m0g = (work & 3) * 96;
    const int t = threadIdx.x;
    const int lane = t & 63, wv = t >> 6;
    const int lr = lane & 15, lk = lane >> 4;
    const int wq = wv;

    const int ar = t >> 2, akc = t & 3;
    const int aq = q0 + ar;
    const bool qvr = (aq < Q);
    const float* arow = x + (size_t)(qvr ? aq : 0) * 720;   // clamped row

    const unsigned short* bsrc[3];
#pragma unroll
    for (int i = 0; i < 3; ++i) {
        int id = t + i * 256;
        int tab = id / 384, rem = id % 384;
        int kc = rem / 96, r = rem % 96;
        bsrc[i] = (tab ? El : Eh) + (size_t)(m0g + r) * 384 + kc * 8;
    }

    f32x4 acc[6];
#pragma unroll
    for (int nj = 0; nj < 6; ++nj)
#pragma unroll
        for (int r = 0; r < 4; ++r) acc[nj][r] = 0.f;

    // 2-deep A raw prefetch, ping-pong slots (static indices via full unroll)
    float4 f0a[2], f0b[2], pra[2], prb[2];

    // UNIFORM A load: exactly 4 vector loads per thread, clamped + masked.
    // valid for kg >= 8 (in-loop kg >= 32).
#define S1_LOADA_U(S, K0)                                                  \
    {                                                                      \
        int kg = (K0) + akc * 8;                                           \
        int kf = (kg <= 352) ? kg : 353;                                   \
        float4 t0 = *(const float4*)(arow + kf);                           \
        float4 t1 = *(const float4*)(arow + kf + 4);                       \
        int kr = (kg <= 352) ? kg : 352;                                   \
        float4 r0 = *(const float4*)(arow + 713 - kr);                     \
        float4 r1 = *(const float4*)(arow + 717 - kr);                     \
        if (kg > 352) {                                                    \
            float v360 = (kg == 360) ? t1.w : 0.f;                         \
            t0 = make_float4(v360, 0.f, 0.f, 0.f);                         \
            t1 = make_float4(0.f, 0.f, 0.f, 0.f);                          \
            r0 = t1; r1 = t1;                                              \
        }                                                                  \
        f0a[S] = t0; f0b[S] = t1; pra[S] = r0; prb[S] = r1;                \
    }
    // prologue-only load (kg may be 0); uniformity not needed pre-__syncthreads
#define S1_LOADA_P(S)                                                      \
    {                                                                      \
        int kg = akc * 8;                                                  \
        f0a[S] = *(const float4*)(arow + kg);                              \
        f0b[S] = *(const float4*)(arow + kg + 4);                          \
        if (kg >= 8) {                                                     \
            pra[S] = *(const float4*)(arow + 713 - kg);                    \
            prb[S] = *(const float4*)(arow + 717 - kg);                    \
        } else {                                                           \
            float tm[8];                                                   \
            _Pragma("unroll") for (int i = 0; i < 8; ++i)                  \
                tm[i] = (7 - i >= 1) ? arow[713 + i] : 0.f;                \
            pra[S] = make_float4(tm[0], tm[1], tm[2], tm[3]);              \
            prb[S] = make_float4(tm[4], tm[5], tm[6], tm[7]);              \
        }                                                                  \
    }
#define S1_WRITEA(NB, S)                                                  \
    {                                                                     \
        float y0 = f0a[S].x + prb[S].w, y1 = f0a[S].y + prb[S].z;         \
        float y2 = f0a[S].z + prb[S].y, y3 = f0a[S].w + prb[S].x;         \
        float y4 = f0b[S].x + pra[S].w, y5 = f0b[S].y + pra[S].z;         \
        float y6 = f0b[S].z + pra[S].y, y7 = f0b[S].w + pra[S].x;         \
        if (!qvr) { y0=y1=y2=y3=0.f; y4=y5=y6=y7=0.f; }                   \
        unsigned int h0, h1, h2, h3, l0, l1, l2, l3;                      \
        split2t(y0, y1, h0, l0);                                          \
        split2t(y2, y3, h1, l1);                                          \
        split2t(y4, y5, h2, l2);                                          \
        split2t(y6, y7, h3, l3);                                          \
        *(uint4*)&Ah[NB][akc][ar][0] = make_uint4(h0, h1, h2, h3);        \
        *(uint4*)&Al[NB][akc][ar][0] = make_uint4(l0, l1, l2, l3);        \
    }
#define S1_COPYB(NB, K0)                                                  \
    {                                                                     \
        char* bb = (char*)&Bt[NB][0][0][0][0];                            \
        _Pragma("unroll") for (int i = 0; i < 3; ++i) {                   \
            gload_lds16(bsrc[i] + (K0), bb + (t + i * 256) * 16);         \
        }                                                                 \
    }
    // counted barrier: drain DMAs (+lgkm), keep newest N vmem ops in flight
#define S1_CBAR(NSTR)                                                     \
    {                                                                     \
        asm volatile("s_waitcnt vmcnt(" NSTR ") lgkmcnt(0)" ::: "memory"); \
        __builtin_amdgcn_s_barrier();                                     \
        __builtin_amdgcn_sched_barrier(0);                                \
    }

    // prologue: B(k0) DMA; A(k0) -> slot0 -> LDS buf0; A(k1) -> slot1
    S1_COPYB(0, 0);
    S1_LOADA_P(0);
    S1_WRITEA(0, 0);
    S1_LOADA_U(1, 32);
    __syncthreads();   // full drain once (prologue only)

#pragma unroll
    for (int it = 0; it < 12; ++it) {
        const int cb = it & 1;        // buffer holding k-block `it`
        const int nb = cb ^ 1;
        if (it + 1 < 12) {
            S1_COPYB(nb, (it + 1) * 32);          // 3 DMAs first...
            __builtin_amdgcn_sched_barrier(0);    // ...pinned before A loads
        }
        if (it + 2 < 12) S1_LOADA_U(((it) & 1), (it + 2) * 32);
        bf16x8 ah = *(const bf16x8*)&Ah[cb][lk][wq * 16 + lr][0];
        bf16x8 al = *(const bf16x8*)&Al[cb][lk][wq * 16 + lr][0];
#pragma unroll
        for (int nj = 0; nj < 6; ++nj) {
            bf16x8 bh = *(const bf16x8*)&Bt[cb][0][lk][nj * 16 + lr][0];
            bf16x8 bl = *(const bf16x8*)&Bt[cb][1][lk][nj * 16 + lr][0];
            acc[nj] = __builtin_amdgcn_mfma_f32_16x16x32_bf16(ah, bh, acc[nj], 0, 0, 0);
            acc[nj] = __builtin_amdgcn_mfma_f32_16x16x32_bf16(ah, bl, acc[nj], 0, 0, 0);
            acc[nj] = __builtin_amdgcn_mfma_f32_16x16x32_bf16(al, bh, acc[nj], 0, 0, 0);
        }
        if (it + 1 < 12) {
            S1_WRITEA(nb, ((it + 1) & 1));
            if (it + 2 < 12) {
                S1_CBAR("4");    // leave the 4 A-loads (it+2) in flight
            } else {
                S1_CBAR("0");    // tail: only DMAs outstanding
            }
        }
    }

    // epilogue: D col=m, row=q (verified mapping); packed (hi,lo) plane
#pragma unroll
    for (int nj = 0; nj < 6; ++nj) {
        int m = m0g + nj * 16 + lr;
        if (m >= 361) continue;
        size_t base = (size_t)m * Q;
#pragma unroll
        for (int reg = 0; reg < 4; ++reg) {
            int q = q0 + wq * 16 + lk * 4 + reg;
            if (q < Q) xrp[base + q] = packhl(acc[nj][reg]);
        }
    }
}

// ---------------- stage 2: per-m GEMM, tile 128bc x 64l (R14/R20 proven form) ----------------
__global__ __launch_bounds__(256, 4) void s2_mfma(
    const unsigned int* __restrict__ xrp, const float* __restrict__ W,
    float* __restrict__ stg, const int CH) {
    __shared__ short Ah[128][40], Al[128][40];   // 10 KB each
    __shared__ short Bh[64][40], Bl[64][40];     // 5 KB each -> 30 KB

    const int work = xcd_work(blockIdx.x, gridDim.x);
    const int m = work / 12;
    const int rem = work % 12;
    const int half = rem / 6, lt = rem % 6;
    const int l0 = lt * 64;
    if (l0 + 63 < m) return;          // dead tile: zero-filled by transpose
    const int bcbase = half * 128;
    if (bcbase >= CH) return;
    const int Q = CH * 361;
    const int t = threadIdx.x;
    const int lane = t & 63, wv = t >> 6;
    const int lr = lane & 15, lk = lane >> 4;
    const int wbc = wv >> 1, wl = wv & 1;

    const unsigned int* Am = xrp + (size_t)m * Q;
    const float* Wm = W + (size_t)m * 130321;

    f32x4 acc[4][2];
#pragma unroll
    for (int fi = 0; fi < 4; ++fi)
#pragma unroll
        for (int ni = 0; ni < 2; ++ni)
#pragma unroll
            for (int r = 0; r < 4; ++r) acc[fi][ni][r] = 0.f;

    unsigned int pa0[8], pa1[8];
    float wva[4], wvb[4];

#define S2_LOADR(K0)                                                          \
    {                                                                         \
        _Pragma("unroll") for (int i = 0; i < 8; ++i) {                       \
            int id = t + i * 256;                                             \
            int r = id >> 4, kp = id & 15;                                    \
            int bc = bcbase + r, kg = (K0) + kp * 2;                          \
            unsigned int p0 = 0, p1 = 0;                                      \
            if (bc < CH) {                                                    \
                size_t base = (size_t)bc * 361;                               \
                if (kg < 361) p0 = Am[base + kg];                             \
                if (kg + 1 < 361) p1 = Am[base + kg + 1];                     \
            }                                                                 \
            pa0[i] = p0; pa1[i] = p1;                                         \
        }                                                                     \
        _Pragma("unroll") for (int i = 0; i < 4; ++i) {                       \
            int id = t + i * 256;                                             \
            int r = id >> 4, kp = id & 15;                                    \
            int l = l0 + r, kg = (K0) + kp * 2;                               \
            float va = 0.f, vb = 0.f;                                         \
            if (l < 361) {                                                    \
                size_t base = (size_t)l * 361;                                \
                if (kg < 361) va = Wm[base + kg];                             \
                if (kg + 1 < 361) vb = Wm[base + kg + 1];                     \
            }                                                                 \
            wva[i] = va; wvb[i] = vb;                                         \
        }                                                                     \
    }
#define S2_WRITES()                                                           \
    {                                                                         \
        _Pragma("unroll") for (int i = 0; i < 8; ++i) {                       \
            int id = t + i * 256;                                             \
            int r = id >> 4, kp = id & 15;                                    \
            *(unsigned int*)&Ah[r][kp * 2] =                                  \
                (pa0[i] & 0xffffu) | (pa1[i] << 16);                          \
            *(unsigned int*)&Al[r][kp * 2] =                                  \
                (pa0[i] >> 16) | (pa1[i] & 0xffff0000u);                      \
        }                                                                     \
        _Pragma("unroll") for (int i = 0; i < 4; ++i) {                       \
            int id = t + i * 256;                                             \
            int r = id >> 4, kp = id & 15;                                    \
            unsigned int hh, ll;                                              \
            split2(wva[i], wvb[i], hh, ll);                                   \
            *(unsigned int*)&Bh[r][kp * 2] = hh;                              \
            *(unsigned int*)&Bl[r][kp * 2] = ll;                              \
        }                                                                     \
    }

    S2_LOADR(0);
    S2_WRITES();
    __syncthreads();
    for (int it = 0; it < 12; ++it) {
        if (it + 1 < 12) S2_LOADR((it + 1) * 32);
#pragma unroll
        for (int fi = 0; fi < 4; ++fi) {
            bf16x8 ah = *(const bf16x8*)&Ah[wbc * 64 + fi * 16 + lr][lk * 8];
            bf16x8 al = *(const bf16x8*)&Al[wbc * 64 + fi * 16 + lr][lk * 8];
#pragma unroll
            for (int ni = 0; ni < 2; ++ni) {
                bf16x8 bh = *(const bf16x8*)&Bh[wl * 32 + ni * 16 + lr][lk * 8];
                bf16x8 bl = *(const bf16x8*)&Bl[wl * 32 + ni * 16 + lr][lk * 8];
                acc[fi][ni] = __builtin_amdgcn_mfma_f32_16x16x32_bf16(ah, bh, acc[fi][ni], 0, 0, 0);
                acc[fi][ni] = __builtin_amdgcn_mfma_f32_16x16x32_bf16(ah, bl, acc[fi][ni], 0, 0, 0);
                acc[fi][ni] = __builtin_amdgcn_mfma_f32_16x16x32_bf16(al, bh, acc[fi][ni], 0, 0, 0);
            }
        }
        __syncthreads();
        if (it + 1 < 12) {
            S2_WRITES();
            __syncthreads();
        }
    }

    // epilogue: stg[(m*CH+bc)*361+l]
#pragma unroll
    for (int fi = 0; fi < 4; ++fi) {
#pragma unroll
        for (int ni = 0; ni < 2; ++ni) {
            int l = l0 + wl * 32 + ni * 16 + lr;
#pragma unroll
            for (int reg = 0; reg < 4; ++reg) {
                int bc = bcbase + wbc * 64 + fi * 16 + lk * 4 + reg;
                if (bc < CH && l < 361)
                    stg[((size_t)m * CH + bc) * 361 + l] = acc[fi][ni][reg];
            }
        }
    }
}

// ---------------- transpose stg [m][q'] -> out, zero-filling dead tiles ----------------
__global__ __launch_bounds__(256) void transpose_out(const float* __restrict__ stg,
                                                     float* __restrict__ out,
                                                     const int c0, const int CH) {
    __shared__ float tile[32][33];
    const int Q = CH * 361;
    const int m0 = blockIdx.y * 32, q0 = blockIdx.x * 32;
    const int tx = threadIdx.x & 31, ty = threadIdx.x >> 5;
    for (int i = ty; i < 32; i += 8) {
        int mm = m0 + i, q = q0 + tx;
        float v = 0.f;
        if (mm < 361 && q < Q) {
            int l = q % 361;
            if ((l | 63) >= mm) v = stg[(size_t)mm * Q + q];  // live 64-tile
        }
        tile[i][tx] = v;
    }
    __syncthreads();
    for (int i = ty; i < 32; i += 8) {
        int q = q0 + i, mm = m0 + tx;
        if (mm < 361 && q < Q)
            out[((size_t)c0 * 361 + q) * 361 + mm] = tile[tx][i];
    }
}

extern "C" void kernel_launch(void* const* d_in, const int* in_sizes, int n_in,
                              void* d_out, int out_size, void* d_ws, size_t ws_size,
                              hipStream_t stream) {
    (void)out_size;
    // select inputs by element count: x = 66,539,520; W = 47,045,881
    const float* x = (const float*)d_in[0];
    const float* W = (const float*)d_in[1];
    if (n_in >= 2 && (in_sizes[0] == 47045881 || in_sizes[1] == 66539520)) {
        x = (const float*)d_in[1];
        W = (const float*)d_in[0];
    }
    float* out = (float*)d_out;

    // ws layout (bytes): EcT_hi [384][384] | EcT_lo | xrp (uint) | stg (f32)
    const size_t offEh = 0;
    const size_t offEl = 294912;                 // 384*384*2
    const size_t offData = 589824;

    const int cands[6] = {256, 128, 64, 32, 16, 8};
    int CH = 0;
    for (int i = 0; i < 6; ++i) {
        size_t need = offData + 2ull * cands[i] * 130321ull * 4ull;
        if (need <= ws_size) { CH = cands[i]; break; }
    }
    if (!CH) return;  // workspace too small: fail visibly, don't fault

    unsigned short* Eh = (unsigned short*)((char*)d_ws + offEh);
    unsigned short* El = (unsigned short*)((char*)d_ws + offEl);
    unsigned int* xrp = (unsigned int*)((char*)d_ws + offData);
    float* stg = (float*)((char*)d_ws + offData + (size_t)CH * 130321ull * 4ull);

    build_ect<<<256, 256, 0, stream>>>(Eh, El);

    const int Q = CH * 361;
    const int qt = (Q + 63) / 64;
    for (int c0 = 0; c0 < 256; c0 += CH) {
        s1_mfma<<<qt * 4, 256, 0, stream>>>(
            x + (size_t)c0 * 361 * 720, Eh, El, xrp, Q);
        s2_mfma<<<361 * 12, 256, 0, stream>>>(xrp, W, stg, CH);
        transpose_out<<<dim3((Q + 31) / 32, 12), 256, 0, stream>>>(stg, out, c0, CH);
    }
}